// Round 1
// baseline (445.936 us; speedup 1.0000x reference)
//
#include <hip/hip_runtime.h>

#define DHW 192
#define TX 32
#define TY 8
#define ZCH 32
#define NT (TX*TY)      // 256 threads

#define RY  (TY+4)      // 12  img ring rows (halo 2)
#define RXW (TX+4)      // 36  img ring row width
#define EY  (TY+2)      // 10  diff2 rows (halo 1)
#define EX  (TX+2)      // 34  diff2 row width

__global__ __launch_bounds__(NT)
void mind3d_kernel(const float* __restrict__ img, float* __restrict__ out)
{
    __shared__ float ring[3][RY*RXW];   // 5184 B
    __shared__ float Ebuf[6][EY*EX];    // 8160 B
    __shared__ float Tbuf[6][EY*TX];    // 7680 B  -> ~20.5 KB total

    const int tx  = threadIdx.x;
    const int ty  = threadIdx.y;
    const int tid = ty*TX + tx;

    const int x0 = blockIdx.x * TX;
    const int y0 = blockIdx.y * TY;
    const int zi = blockIdx.z;              // 0..11
    const int b  = zi / (DHW/ZCH);          // batch 0..1
    const int z0 = (zi - b*(DHW/ZCH)) * ZCH;

    const float* imgb = img + (size_t)b * ((size_t)DHW*DHW*DHW);

    const float a1    = 0.01831563889245986f;      // exp(-4) = exp(-1/sigma^2), sigma^2=0.25
    const float n1    = 1.0f/(1.0f + 2.0f*a1);
    const float norm3 = n1*n1*n1;                  // separable 3D kernel normalization

    // per-thread z-direction ring of in-plane-smoothed slices S(z-1), S(z), S(z+1)
    float sm1[6], s0[6], sp1[6];
    #pragma unroll
    for (int c = 0; c < 6; ++c) { sm1[c] = 0.f; s0[c] = 0.f; }

    auto load_slice = [&](int z) {
        float* dst = ring[(z + 192) % 3];
        if (z < 0 || z >= DHW) {
            for (int i = tid; i < RY*RXW; i += NT) dst[i] = 0.f;
        } else {
            const float* sp = imgb + (size_t)z * (DHW*DHW);
            for (int i = tid; i < RY*RXW; i += NT) {
                int yy = i / RXW, xx = i - yy*RXW;
                int gy = y0 + yy - 2, gx = x0 + xx - 2;
                float v = 0.f;
                if ((unsigned)gy < (unsigned)DHW && (unsigned)gx < (unsigned)DHW)
                    v = sp[gy*DHW + gx];
                dst[i] = v;
            }
        }
    };

    load_slice(z0 - 2);
    load_slice(z0 - 1);

    for (int zs = z0 - 1; zs <= z0 + ZCH; ++zs) {
        // 1. stage img slice zs+1 into ring (zero outside volume)
        load_slice(zs + 1);
        __syncthreads();

        const bool  zvalid = (zs >= 0 && zs < DHW);
        const float* rm = ring[(zs - 1 + 192) % 3];
        const float* rc = ring[(zs     + 192) % 3];
        const float* rp = ring[(zs + 1 + 192) % 3];

        // 2. E = diff^2 for all 6 channels over (EY x EX) halo-1 region
        if (zvalid) {
            for (int i = tid; i < EY*EX; i += NT) {
                int r = i / EX, px = i - r*EX;       // y = y0+r-1, x = x0+px-1
                int gy = y0 + r - 1, gx = x0 + px - 1;
                int q  = (r + 1)*RXW + (px + 1);     // ring coords (halo-2 offset)
                float c0 = rc[q];
                float e0=0.f,e1=0.f,e2=0.f,e3=0.f,e4=0.f,e5=0.f;
                if ((unsigned)gy < (unsigned)DHW && (unsigned)gx < (unsigned)DHW) {
                    float d;
                    d = rp[q]       - c0; e0 = d*d;  // +z
                    d = rm[q]       - c0; e1 = d*d;  // -z
                    d = rc[q + RXW] - c0; e2 = d*d;  // +y
                    d = rc[q - RXW] - c0; e3 = d*d;  // -y
                    d = rc[q + 1]   - c0; e4 = d*d;  // +x
                    d = rc[q - 1]   - c0; e5 = d*d;  // -x
                }
                Ebuf[0][i]=e0; Ebuf[1][i]=e1; Ebuf[2][i]=e2;
                Ebuf[3][i]=e3; Ebuf[4][i]=e4; Ebuf[5][i]=e5;
            }
        }
        __syncthreads();

        // 3. T = x-conv of E (taps [a1, 1, a1], unnormalized)
        if (zvalid) {
            for (int i = tid; i < EY*TX; i += NT) {
                int r = i / TX, x = i - r*TX;
                int e = r*EX + x;
                #pragma unroll
                for (int c = 0; c < 6; ++c)
                    Tbuf[c][i] = a1*(Ebuf[c][e] + Ebuf[c][e + 2]) + Ebuf[c][e + 1];
            }
        }
        __syncthreads();

        // 4. S(zs) = y-conv of T at this thread's (x,y)
        #pragma unroll
        for (int c = 0; c < 6; ++c) {
            float s = 0.f;
            if (zvalid)
                s = a1*(Tbuf[c][ty*TX + tx] + Tbuf[c][(ty + 2)*TX + tx])
                    + Tbuf[c][(ty + 1)*TX + tx];
            sp1[c] = s;
        }

        // 5. emit output at zc = zs-1 (z-conv from register ring + epilogue)
        const int zc = zs - 1;
        if (zc >= z0) {
            float dp[6], sum = 0.f;
            #pragma unroll
            for (int c = 0; c < 6; ++c) {
                dp[c] = norm3 * (a1*(sm1[c] + sp1[c]) + s0[c]);
                sum += dp[c];
            }
            float inv = 1.0f / (sum * (1.0f/6.0f) + 1e-8f);   // 1/(Vx+EPS)
            float num[6], nsum = 0.f;
            #pragma unroll
            for (int c = 0; c < 6; ++c) {
                num[c] = __expf(-dp[c] * inv);
                nsum += num[c];
            }
            float rs = 1.0f / (nsum + 1e-8f);
            size_t base = (((size_t)b*6)*DHW + zc) * ((size_t)DHW*DHW)
                        + (size_t)(y0 + ty)*DHW + (x0 + tx);
            #pragma unroll
            for (int c = 0; c < 6; ++c)
                out[base + (size_t)c * ((size_t)DHW*DHW*DHW)] = num[c] * rs;
        }

        #pragma unroll
        for (int c = 0; c < 6; ++c) { sm1[c] = s0[c]; s0[c] = sp1[c]; }
    }
}

extern "C" void kernel_launch(void* const* d_in, const int* in_sizes, int n_in,
                              void* d_out, int out_size, void* d_ws, size_t ws_size,
                              hipStream_t stream)
{
    const float* img = (const float*)d_in[0];
    float* out = (float*)d_out;
    dim3 block(TX, TY, 1);
    dim3 grid(DHW/TX, DHW/TY, 2*(DHW/ZCH));   // 6 x 24 x 12 = 1728 blocks
    hipLaunchKernelGGL(mind3d_kernel, grid, block, 0, stream, img, out);
}